// Round 2
// baseline (2440.533 us; speedup 1.0000x reference)
//
#include <hip/hip_runtime.h>
#include <hip/hip_bf16.h>
#include <stdint.h>

typedef __bf16 bf16_t;
typedef bf16_t bf16x8 __attribute__((ext_vector_type(8)));
typedef float  f32x4  __attribute__((ext_vector_type(4)));

// ---------------- async global->LDS (16B per lane) ----------------
__device__ __forceinline__ void g2l16(const void* gp, void* lp) {
  __builtin_amdgcn_global_load_lds(
      (const __attribute__((address_space(1))) unsigned int*)(uintptr_t)gp,
      (__attribute__((address_space(3))) unsigned int*)(uint32_t)(uintptr_t)lp,
      16, 0, 0);
}

// ---------------- embed: h[i] = x_emb1[x[i,0]] + x_emb2[x[i,1]] ----------------
// wave per node, lane<40 handles 8 cols; pad cols 300..319 -> 0
__global__ void embed_kernel(const int* __restrict__ x, const float* __restrict__ e1,
                             const float* __restrict__ e2, bf16_t* __restrict__ h, int N) {
  const int w = (blockIdx.x * blockDim.x + threadIdx.x) >> 6;
  const int lane = threadIdx.x & 63;
  if (w >= N || lane >= 40) return;
  const int t0 = x[2 * w], t1 = x[2 * w + 1];
  const int co = lane * 8;
  // safe OOB-by-row reads: t0<11, t1<11, tables have 121/11 rows
  f32x4 a0 = *(const f32x4*)&e1[t0 * 300 + co];
  f32x4 a1 = *(const f32x4*)&e1[t0 * 300 + co + 4];
  f32x4 b0 = *(const f32x4*)&e2[t1 * 300 + co];
  f32x4 b1 = *(const f32x4*)&e2[t1 * 300 + co + 4];
  bf16x8 o;
  #pragma unroll
  for (int j = 0; j < 8; j++) {
    float v = (j < 4) ? (a0[j] + b0[j]) : (a1[j - 4] + b1[j - 4]);
    o[j] = (co + j < 300) ? (bf16_t)v : (bf16_t)0.f;
  }
  *(bf16x8*)&h[(size_t)w * 320 + co] = o;
}

// ---------------- CSR build ----------------
__global__ void count_deg_kernel(const int* __restrict__ ei, int* __restrict__ deg, int E) {
  int e = blockIdx.x * 256 + threadIdx.x;
  if (e < E) atomicAdd(&deg[ei[E + e]], 1);
}

__global__ void scan_partial_kernel(const int* __restrict__ deg, int* __restrict__ part, int N) {
  __shared__ int s[256];
  const int tid = threadIdx.x;
  const int idx = blockIdx.x * 256 + tid;
  s[tid] = (idx < N) ? deg[idx] : 0;
  __syncthreads();
  for (int off = 128; off > 0; off >>= 1) {
    if (tid < off) s[tid] += s[tid + off];
    __syncthreads();
  }
  if (tid == 0) part[blockIdx.x] = s[0];
}

__global__ void scan_block_kernel(int* __restrict__ part, int n) {  // n <= 1024
  __shared__ int s[1024];
  const int tid = threadIdx.x;
  const int v = (tid < n) ? part[tid] : 0;
  s[tid] = v;
  __syncthreads();
  for (int off = 1; off < 1024; off <<= 1) {
    int x = (tid >= off) ? s[tid - off] : 0;
    __syncthreads();
    s[tid] += x;
    __syncthreads();
  }
  if (tid < n) part[tid] = s[tid] - v;  // exclusive
}

__global__ void scan_final_kernel(const int* __restrict__ deg, const int* __restrict__ part,
                                  int* __restrict__ rowptr, int* __restrict__ cursor, int N, int E) {
  __shared__ int s[256];
  const int tid = threadIdx.x;
  const int idx = blockIdx.x * 256 + tid;
  const int v = (idx < N) ? deg[idx] : 0;
  s[tid] = v;
  __syncthreads();
  for (int off = 1; off < 256; off <<= 1) {
    int x = (tid >= off) ? s[tid - off] : 0;
    __syncthreads();
    s[tid] += x;
    __syncthreads();
  }
  if (idx < N) {
    int ex = s[tid] - v + part[blockIdx.x];
    rowptr[idx] = ex;
    cursor[idx] = ex;
  }
  if (idx == 0) rowptr[N] = E;
}

// pack src | (a0*3+a1)<<20
__global__ void fill_csr_kernel(const int* __restrict__ ei, const int* __restrict__ ea,
                                int* __restrict__ cursor, int* __restrict__ epack, int E) {
  int e = blockIdx.x * 256 + threadIdx.x;
  if (e >= E) return;
  int slot = atomicAdd(&cursor[ei[E + e]], 1);
  int a = ea[2 * e] * 3 + ea[2 * e + 1];
  epack[slot] = (ei[e] & 0xFFFFF) | (a << 20);
}

// ---------------- weight convert+transpose+pad to bf16 ----------------
__global__ void convert_w1_kernel(const float* __restrict__ w1, bf16_t* __restrict__ o) {
  int id = blockIdx.x * 256 + threadIdx.x;
  if (id >= 5 * 640 * 320) return;
  int k = id % 320;
  int n = (id / 320) % 640;
  int l = id / (320 * 640);
  float v = (k < 300 && n < 600) ? w1[(size_t)l * 300 * 600 + (size_t)k * 600 + n] : 0.f;
  o[id] = (bf16_t)v;
}

__global__ void convert_w2_kernel(const float* __restrict__ w2, bf16_t* __restrict__ o) {
  int id = blockIdx.x * 256 + threadIdx.x;
  if (id >= 5 * 384 * 640) return;
  int k = id % 640;
  int n = (id / 640) % 384;
  int l = id / (640 * 384);
  float v = (k < 600 && n < 300) ? w2[(size_t)l * 600 * 300 + (size_t)k * 300 + n] : 0.f;
  o[id] = (bf16_t)v;
}

// combined edge table: T12[l][a0*3+a1][col] = ee1[l][a0][col] + ee2[l][a1][col], bf16, pad->0
__global__ void build_t12_kernel(const float* __restrict__ ee1, const float* __restrict__ ee2,
                                 bf16_t* __restrict__ T12) {
  int id = blockIdx.x * 256 + threadIdx.x;
  if (id >= 5 * 21 * 320) return;
  int col = id % 320;
  int r = id / 320;
  int l = r / 21;
  int a = r % 21;
  int a0 = a / 3, a1 = a % 3;
  float v = 0.f;
  if (col < 300) v = ee1[((size_t)l * 7 + a0) * 300 + col] + ee2[((size_t)l * 3 + a1) * 300 + col];
  T12[id] = (bf16_t)v;
}

// ---------------- aggregation: wave per node, CSR gather, bf16x8 ----------------
__global__ void aggregate_kernel(const bf16_t* __restrict__ h, const int* __restrict__ rowptr,
                                 const int* __restrict__ epack, const bf16_t* __restrict__ T12L,
                                 bf16_t* __restrict__ agg, int N) {
  const int w = (blockIdx.x * blockDim.x + threadIdx.x) >> 6;
  const int lane = threadIdx.x & 63;
  if (w >= N || lane >= 40) return;
  const int co = lane * 8;
  const int beg = rowptr[w], end = rowptr[w + 1];
  float acc[8];
  {
    bf16x8 hv = *(const bf16x8*)&h[(size_t)w * 320 + co];
    bf16x8 tv = *(const bf16x8*)&T12L[12 * 320 + co];  // self loop: a0=4,a1=0
    #pragma unroll
    for (int j = 0; j < 8; j++) acc[j] = (float)hv[j] + (float)tv[j];
  }
  for (int e = beg; e < end; e++) {
    const int p = epack[e];
    const int s = p & 0xFFFFF;
    const int a = (p >> 20) & 0x1F;
    bf16x8 hv = *(const bf16x8*)&h[(size_t)s * 320 + co];
    bf16x8 tv = *(const bf16x8*)&T12L[a * 320 + co];
    #pragma unroll
    for (int j = 0; j < 8; j++) acc[j] += (float)hv[j] + (float)tv[j];
  }
  bf16x8 o;
  #pragma unroll
  for (int j = 0; j < 8; j++) o[j] = (bf16_t)acc[j];
  *(bf16x8*)&agg[(size_t)w * 320 + co] = o;
}

// ---------------- GEMM1: [Mp,320] x W1T[640,320] -> C1[Mp,640], bias+ReLU ----------------
// A-stationary: full-K A tile (128x320, XOR-swizzled) in LDS once; B frags direct from
// global (L2-resident); n-loop over 5 chunks of 128; zero barriers in K-loop.
__global__ __launch_bounds__(256) void gemm1_kernel(const bf16_t* __restrict__ A,
                                                    const bf16_t* __restrict__ BT,
                                                    const float* __restrict__ bias,
                                                    bf16_t* __restrict__ C) {
  __shared__ __align__(16) bf16_t As[128 * 320];  // 80 KB
  const int tid = threadIdx.x;
  const int lane = tid & 63;
  const int wave = tid >> 6;
  const int ml = lane & 15, quad = lane >> 4;
  const int wm = (wave & 1) * 64, wn = (wave >> 1) * 64;
  const int sel = ml & 7;
  const size_t bm = (size_t)blockIdx.x * 128;

  // stage A 128x320 with 16B-chunk XOR swizzle: LDS pos (row,c) holds global chunk
  // (c&~7)|((c&7)^(row&7))
  #pragma unroll
  for (int it = 0; it < 20; it++) {
    int p = it * 256 + tid;
    int row = p / 40;
    int c = p - row * 40;
    int g = (c & ~7) | ((c & 7) ^ (row & 7));
    g2l16(A + ((bm + row) * 320 + g * 8), (void*)&As[(size_t)p * 8]);
  }
  __syncthreads();

  for (int nc = 0; nc < 5; nc++) {
    const int bn0 = nc * 128 + wn;
    f32x4 acc[4][4];
    #pragma unroll
    for (int r = 0; r < 4; r++)
      #pragma unroll
      for (int c = 0; c < 4; c++) acc[r][c] = (f32x4){0.f, 0.f, 0.f, 0.f};

    #pragma unroll 2
    for (int kb = 0; kb < 10; kb++) {
      const int cc = kb * 4 + quad;
      const int cp = (cc & ~7) | ((cc & 7) ^ sel);
      bf16x8 aF[4], bF[4];
      #pragma unroll
      for (int nf = 0; nf < 4; nf++)
        bF[nf] = *(const bf16x8*)&BT[(size_t)(bn0 + nf * 16 + ml) * 320 + kb * 32 + quad * 8];
      #pragma unroll
      for (int mf = 0; mf < 4; mf++)
        aF[mf] = *(const bf16x8*)&As[(wm + mf * 16 + ml) * 320 + cp * 8];
      #pragma unroll
      for (int mf = 0; mf < 4; mf++)
        #pragma unroll
        for (int nf = 0; nf < 4; nf++)
          acc[mf][nf] = __builtin_amdgcn_mfma_f32_16x16x32_bf16(aF[mf], bF[nf], acc[mf][nf], 0, 0, 0);
    }

    #pragma unroll
    for (int nf = 0; nf < 4; nf++) {
      const int colg = bn0 + nf * 16 + ml;
      const float bv = (colg < 600) ? bias[colg] : 0.f;
      #pragma unroll
      for (int mf = 0; mf < 4; mf++) {
        #pragma unroll
        for (int i = 0; i < 4; i++) {
          const size_t rowg = bm + wm + mf * 16 + quad * 4 + i;
          float v = acc[mf][nf][i] + bv;
          v = fmaxf(v, 0.f);
          C[rowg * 640 + colg] = (bf16_t)v;
        }
      }
    }
  }
}

// ---------------- GEMM2: [Mp,640] x W2T[384,640] -> H2[Mp,384], bias ----------------
// 32-row blocks (40KB LDS, 4 blk/CU), waves split N (wave w -> cols w*32..+32).
__global__ __launch_bounds__(256) void gemm2_kernel(const bf16_t* __restrict__ A,
                                                    const bf16_t* __restrict__ BT,
                                                    const float* __restrict__ bias,
                                                    bf16_t* __restrict__ C) {
  __shared__ __align__(16) bf16_t As[32 * 640];  // 40 KB
  const int tid = threadIdx.x;
  const int lane = tid & 63;
  const int wave = tid >> 6;
  const int ml = lane & 15, quad = lane >> 4;
  const int sel = ml & 7;
  const size_t bm = (size_t)blockIdx.x * 32;

  #pragma unroll
  for (int it = 0; it < 10; it++) {
    int p = it * 256 + tid;
    int row = p / 80;
    int c = p - row * 80;
    int g = (c & ~7) | ((c & 7) ^ (row & 7));
    g2l16(A + ((bm + row) * 640 + g * 8), (void*)&As[(size_t)p * 8]);
  }
  __syncthreads();

  for (int nc = 0; nc < 3; nc++) {
    const int bn0 = nc * 128 + wave * 32;
    f32x4 acc[2][2];
    #pragma unroll
    for (int r = 0; r < 2; r++)
      #pragma unroll
      for (int c = 0; c < 2; c++) acc[r][c] = (f32x4){0.f, 0.f, 0.f, 0.f};

    #pragma unroll 4
    for (int kb = 0; kb < 20; kb++) {
      const int cc = kb * 4 + quad;
      const int cp = (cc & ~7) | ((cc & 7) ^ sel);
      bf16x8 aF[2], bF[2];
      #pragma unroll
      for (int nf = 0; nf < 2; nf++)
        bF[nf] = *(const bf16x8*)&BT[(size_t)(bn0 + nf * 16 + ml) * 640 + kb * 32 + quad * 8];
      #pragma unroll
      for (int mf = 0; mf < 2; mf++)
        aF[mf] = *(const bf16x8*)&As[(mf * 16 + ml) * 640 + cp * 8];
      #pragma unroll
      for (int mf = 0; mf < 2; mf++)
        #pragma unroll
        for (int nf = 0; nf < 2; nf++)
          acc[mf][nf] = __builtin_amdgcn_mfma_f32_16x16x32_bf16(aF[mf], bF[nf], acc[mf][nf], 0, 0, 0);
    }

    #pragma unroll
    for (int nf = 0; nf < 2; nf++) {
      const int colg = bn0 + nf * 16 + ml;
      const float bv = (colg < 300) ? bias[colg] : 0.f;
      #pragma unroll
      for (int mf = 0; mf < 2; mf++) {
        #pragma unroll
        for (int i = 0; i < 4; i++) {
          const size_t rowg = bm + mf * 16 + quad * 4 + i;
          C[rowg * 384 + colg] = (bf16_t)(acc[mf][nf][i] + bv);
        }
      }
    }
  }
}

// ---------------- BN ----------------
__global__ void bn_stats_kernel(const bf16_t* __restrict__ H2, float* __restrict__ sums,
                                float* __restrict__ sumsq, int N) {
  const int col = threadIdx.x;
  if (col >= 300) return;
  const int r0 = blockIdx.x * 128;
  const int r1 = (r0 + 128 < N) ? r0 + 128 : N;
  float s = 0.f, ss = 0.f;
  #pragma unroll 4
  for (int r = r0; r < r1; r++) {
    float v = (float)H2[(size_t)r * 384 + col];
    s += v;
    ss += v * v;
  }
  atomicAdd(&sums[col], s);
  atomicAdd(&sumsq[col], ss);
}

__global__ void bn_params_kernel(const float* __restrict__ sums, const float* __restrict__ sumsq,
                                 const float* __restrict__ gamma, const float* __restrict__ beta,
                                 float* __restrict__ scale, float* __restrict__ shift, int N) {
  const int col = threadIdx.x;
  if (col >= 384) return;
  if (col >= 300) {  // pad cols: force h pad to 0
    scale[col] = 0.f;
    shift[col] = 0.f;
    return;
  }
  const float inv = 1.f / (float)N;
  const float mean = sums[col] * inv;
  float var = sumsq[col] * inv - mean * mean;
  if (var < 0.f) var = 0.f;
  const float sc = gamma[col] * rsqrtf(var + 1e-5f);
  scale[col] = sc;
  shift[col] = beta[col] - mean * sc;
}

// wave per node, lane<40 handles 8 cols
__global__ void bn_apply_kernel(const bf16_t* __restrict__ H2, const float* __restrict__ scale,
                                const float* __restrict__ shift, bf16_t* __restrict__ h,
                                float* __restrict__ out, int relu, int last, int N) {
  const int w = (blockIdx.x * blockDim.x + threadIdx.x) >> 6;
  const int lane = threadIdx.x & 63;
  if (w >= N || lane >= 40) return;
  const int co = lane * 8;
  bf16x8 v8 = *(const bf16x8*)&H2[(size_t)w * 384 + co];
  f32x4 s0 = *(const f32x4*)&scale[co];
  f32x4 s1 = *(const f32x4*)&scale[co + 4];
  f32x4 t0 = *(const f32x4*)&shift[co];
  f32x4 t1 = *(const f32x4*)&shift[co + 4];
  float vv[8];
  #pragma unroll
  for (int j = 0; j < 8; j++) {
    float sc = (j < 4) ? s0[j] : s1[j - 4];
    float sh = (j < 4) ? t0[j] : t1[j - 4];
    float v = (float)v8[j] * sc + sh;
    if (relu) v = fmaxf(v, 0.f);
    vv[j] = v;
  }
  if (!last) {
    bf16x8 o;
    #pragma unroll
    for (int j = 0; j < 8; j++) o[j] = (bf16_t)vv[j];
    *(bf16x8*)&h[(size_t)w * 320 + co] = o;
  } else {
    #pragma unroll
    for (int j = 0; j < 8; j++)
      if (co + j < 300) out[(size_t)w * 300 + co + j] = vv[j];
  }
}

// ---------------- launch ----------------
extern "C" void kernel_launch(void* const* d_in, const int* in_sizes, int n_in,
                              void* d_out, int out_size, void* d_ws, size_t ws_size,
                              hipStream_t stream) {
  const int* x = (const int*)d_in[0];
  const int* ei = (const int*)d_in[1];
  const int* ea = (const int*)d_in[2];
  const float* xe1 = (const float*)d_in[3];
  const float* xe2 = (const float*)d_in[4];
  const float* ee1 = (const float*)d_in[5];
  const float* ee2 = (const float*)d_in[6];
  const float* w1 = (const float*)d_in[7];
  const float* b1 = (const float*)d_in[8];
  const float* w2 = (const float*)d_in[9];
  const float* b2 = (const float*)d_in[10];
  const float* gam = (const float*)d_in[11];
  const float* bet = (const float*)d_in[12];

  const int N = in_sizes[0] / 2;   // 100000
  const int E = in_sizes[1] / 2;   // 200000
  const int Mt = (N + 127) / 128;  // 782
  const size_t Mp = (size_t)Mt * 128;

  char* p = (char*)d_ws;
  auto take = [&](size_t b) -> char* {
    char* r = p;
    p += (b + 255) & ~(size_t)255;
    return r;
  };
  bf16_t* h    = (bf16_t*)take(Mp * 320 * 2);
  bf16_t* agg  = (bf16_t*)take(Mp * 320 * 2);
  bf16_t* C1   = (bf16_t*)take(Mp * 640 * 2);
  bf16_t* H2   = (bf16_t*)take(Mp * 384 * 2);
  bf16_t* W1bT = (bf16_t*)take((size_t)5 * 640 * 320 * 2);
  bf16_t* W2bT = (bf16_t*)take((size_t)5 * 384 * 640 * 2);
  bf16_t* T12  = (bf16_t*)take((size_t)5 * 21 * 320 * 2);
  int* deg     = (int*)take((size_t)N * 4);
  int* rowptr  = (int*)take((size_t)(N + 1) * 4);
  int* cursor  = (int*)take((size_t)N * 4);
  int* part    = (int*)take(1024 * 4);
  int* epack   = (int*)take((size_t)E * 4);
  float* sums  = (float*)take(384 * 4);
  float* sumsq = (float*)take(384 * 4);
  float* scale = (float*)take(384 * 4);
  float* shift = (float*)take(384 * 4);

  // agg pad rows must be exact zeros for GEMM1 (done once; aggregate writes rows<N only)
  hipMemsetAsync(agg, 0, Mp * 320 * 2, stream);
  hipMemsetAsync(deg, 0, (size_t)N * 4, stream);

  const int nwb = (N + 3) / 4;  // wave-per-node, 4 waves per 256-thread block
  embed_kernel<<<nwb, 256, 0, stream>>>(x, xe1, xe2, h, N);

  count_deg_kernel<<<(E + 255) / 256, 256, 0, stream>>>(ei, deg, E);
  const int nsb = (N + 255) / 256;  // 391 (<=1024 required by scan_block)
  scan_partial_kernel<<<nsb, 256, 0, stream>>>(deg, part, N);
  scan_block_kernel<<<1, 1024, 0, stream>>>(part, nsb);
  scan_final_kernel<<<nsb, 256, 0, stream>>>(deg, part, rowptr, cursor, N, E);
  fill_csr_kernel<<<(E + 255) / 256, 256, 0, stream>>>(ei, ea, cursor, epack, E);

  convert_w1_kernel<<<(5 * 640 * 320 + 255) / 256, 256, 0, stream>>>(w1, W1bT);
  convert_w2_kernel<<<(5 * 384 * 640 + 255) / 256, 256, 0, stream>>>(w2, W2bT);
  build_t12_kernel<<<(5 * 21 * 320 + 255) / 256, 256, 0, stream>>>(ee1, ee2, T12);

  for (int l = 0; l < 5; l++) {
    aggregate_kernel<<<nwb, 256, 0, stream>>>(h, rowptr, epack, T12 + (size_t)l * 21 * 320,
                                              agg, N);
    gemm1_kernel<<<Mt, 256, 0, stream>>>(agg, W1bT + (size_t)l * 640 * 320,
                                         b1 + (size_t)l * 600, C1);
    gemm2_kernel<<<Mt * 4, 256, 0, stream>>>(C1, W2bT + (size_t)l * 384 * 640,
                                             b2 + (size_t)l * 300, H2);
    hipMemsetAsync(sums, 0, 384 * 4, stream);
    hipMemsetAsync(sumsq, 0, 384 * 4, stream);
    bn_stats_kernel<<<Mt, 320, 0, stream>>>(H2, sums, sumsq, N);
    bn_params_kernel<<<1, 384, 0, stream>>>(sums, sumsq, gam + (size_t)l * 300,
                                            bet + (size_t)l * 300, scale, shift, N);
    bn_apply_kernel<<<nwb, 256, 0, stream>>>(H2, scale, shift, h, (float*)d_out,
                                             (l < 4) ? 1 : 0, (l == 4) ? 1 : 0, N);
  }
}

// Round 3
// 1720.135 us; speedup vs baseline: 1.4188x; 1.4188x over previous
//
#include <hip/hip_runtime.h>
#include <hip/hip_bf16.h>
#include <stdint.h>

typedef __bf16 bf16_t;
typedef bf16_t bf16x8 __attribute__((ext_vector_type(8)));
typedef float  f32x4  __attribute__((ext_vector_type(4)));

// ---------------- async global->LDS (16B per lane) ----------------
__device__ __forceinline__ void g2l16(const void* gp, void* lp) {
  __builtin_amdgcn_global_load_lds(
      (const __attribute__((address_space(1))) unsigned int*)(uintptr_t)gp,
      (__attribute__((address_space(3))) unsigned int*)(uint32_t)(uintptr_t)lp,
      16, 0, 0);
}

// ---------------- embed: h[i] = x_emb1[x[i,0]] + x_emb2[x[i,1]] ----------------
__global__ void embed_kernel(const int* __restrict__ x, const float* __restrict__ e1,
                             const float* __restrict__ e2, bf16_t* __restrict__ h, int N) {
  const int w = (blockIdx.x * blockDim.x + threadIdx.x) >> 6;
  const int lane = threadIdx.x & 63;
  if (w >= N || lane >= 40) return;
  const int t0 = x[2 * w], t1 = x[2 * w + 1];
  const int co = lane * 8;
  f32x4 a0 = *(const f32x4*)&e1[t0 * 300 + co];
  f32x4 a1 = *(const f32x4*)&e1[t0 * 300 + co + 4];
  f32x4 b0 = *(const f32x4*)&e2[t1 * 300 + co];
  f32x4 b1 = *(const f32x4*)&e2[t1 * 300 + co + 4];
  bf16x8 o;
  #pragma unroll
  for (int j = 0; j < 8; j++) {
    float v = (j < 4) ? (a0[j] + b0[j]) : (a1[j - 4] + b1[j - 4]);
    o[j] = (co + j < 300) ? (bf16_t)v : (bf16_t)0.f;
  }
  *(bf16x8*)&h[(size_t)w * 320 + co] = o;
}

// ---------------- CSR build ----------------
__global__ void count_deg_kernel(const int* __restrict__ ei, int* __restrict__ deg, int E) {
  int e = blockIdx.x * 256 + threadIdx.x;
  if (e < E) atomicAdd(&deg[ei[E + e]], 1);
}

__global__ void scan_partial_kernel(const int* __restrict__ deg, int* __restrict__ part, int N) {
  __shared__ int s[256];
  const int tid = threadIdx.x;
  const int idx = blockIdx.x * 256 + tid;
  s[tid] = (idx < N) ? deg[idx] : 0;
  __syncthreads();
  for (int off = 128; off > 0; off >>= 1) {
    if (tid < off) s[tid] += s[tid + off];
    __syncthreads();
  }
  if (tid == 0) part[blockIdx.x] = s[0];
}

__global__ void scan_block_kernel(int* __restrict__ part, int n) {  // n <= 1024
  __shared__ int s[1024];
  const int tid = threadIdx.x;
  const int v = (tid < n) ? part[tid] : 0;
  s[tid] = v;
  __syncthreads();
  for (int off = 1; off < 1024; off <<= 1) {
    int x = (tid >= off) ? s[tid - off] : 0;
    __syncthreads();
    s[tid] += x;
    __syncthreads();
  }
  if (tid < n) part[tid] = s[tid] - v;  // exclusive
}

__global__ void scan_final_kernel(const int* __restrict__ deg, const int* __restrict__ part,
                                  int* __restrict__ rowptr, int* __restrict__ cursor, int N, int E) {
  __shared__ int s[256];
  const int tid = threadIdx.x;
  const int idx = blockIdx.x * 256 + tid;
  const int v = (idx < N) ? deg[idx] : 0;
  s[tid] = v;
  __syncthreads();
  for (int off = 1; off < 256; off <<= 1) {
    int x = (tid >= off) ? s[tid - off] : 0;
    __syncthreads();
    s[tid] += x;
    __syncthreads();
  }
  if (idx < N) {
    int ex = s[tid] - v + part[blockIdx.x];
    rowptr[idx] = ex;
    cursor[idx] = ex;
  }
  if (idx == 0) rowptr[N] = E;
}

// pack src | (a0*3+a1)<<20
__global__ void fill_csr_kernel(const int* __restrict__ ei, const int* __restrict__ ea,
                                int* __restrict__ cursor, int* __restrict__ epack, int E) {
  int e = blockIdx.x * 256 + threadIdx.x;
  if (e >= E) return;
  int slot = atomicAdd(&cursor[ei[E + e]], 1);
  int a = ea[2 * e] * 3 + ea[2 * e + 1];
  epack[slot] = (ei[e] & 0xFFFFF) | (a << 20);
}

// ---------------- weight convert+transpose+pad to bf16 ----------------
__global__ void convert_w1_kernel(const float* __restrict__ w1, bf16_t* __restrict__ o) {
  int id = blockIdx.x * 256 + threadIdx.x;
  if (id >= 5 * 640 * 320) return;
  int k = id % 320;
  int n = (id / 320) % 640;
  int l = id / (320 * 640);
  float v = (k < 300 && n < 600) ? w1[(size_t)l * 300 * 600 + (size_t)k * 600 + n] : 0.f;
  o[id] = (bf16_t)v;
}

__global__ void convert_w2_kernel(const float* __restrict__ w2, bf16_t* __restrict__ o) {
  int id = blockIdx.x * 256 + threadIdx.x;
  if (id >= 5 * 384 * 640) return;
  int k = id % 640;
  int n = (id / 640) % 384;
  int l = id / (640 * 384);
  float v = (k < 600 && n < 300) ? w2[(size_t)l * 600 * 300 + (size_t)k * 300 + n] : 0.f;
  o[id] = (bf16_t)v;
}

// combined edge table: T12[l][a0*3+a1][col] = ee1[l][a0][col] + ee2[l][a1][col]
__global__ void build_t12_kernel(const float* __restrict__ ee1, const float* __restrict__ ee2,
                                 bf16_t* __restrict__ T12) {
  int id = blockIdx.x * 256 + threadIdx.x;
  if (id >= 5 * 21 * 320) return;
  int col = id % 320;
  int r = id / 320;
  int l = r / 21;
  int a = r % 21;
  int a0 = a / 3, a1 = a % 3;
  float v = 0.f;
  if (col < 300) v = ee1[((size_t)l * 7 + a0) * 300 + col] + ee2[((size_t)l * 3 + a1) * 300 + col];
  T12[id] = (bf16_t)v;
}

// ---------------- aggregation: wave per node, CSR gather, bf16x8 ----------------
__global__ void aggregate_kernel(const bf16_t* __restrict__ h, const int* __restrict__ rowptr,
                                 const int* __restrict__ epack, const bf16_t* __restrict__ T12L,
                                 bf16_t* __restrict__ agg, int N) {
  const int w = (blockIdx.x * blockDim.x + threadIdx.x) >> 6;
  const int lane = threadIdx.x & 63;
  if (w >= N || lane >= 40) return;
  const int co = lane * 8;
  const int beg = rowptr[w], end = rowptr[w + 1];
  float acc[8];
  {
    bf16x8 hv = *(const bf16x8*)&h[(size_t)w * 320 + co];
    bf16x8 tv = *(const bf16x8*)&T12L[12 * 320 + co];  // self loop: a0=4,a1=0
    #pragma unroll
    for (int j = 0; j < 8; j++) acc[j] = (float)hv[j] + (float)tv[j];
  }
  for (int e = beg; e < end; e++) {
    const int p = epack[e];
    const int s = p & 0xFFFFF;
    const int a = (p >> 20) & 0x1F;
    bf16x8 hv = *(const bf16x8*)&h[(size_t)s * 320 + co];
    bf16x8 tv = *(const bf16x8*)&T12L[a * 320 + co];
    #pragma unroll
    for (int j = 0; j < 8; j++) acc[j] += (float)hv[j] + (float)tv[j];
  }
  bf16x8 o;
  #pragma unroll
  for (int j = 0; j < 8; j++) o[j] = (bf16_t)acc[j];
  *(bf16x8*)&agg[(size_t)w * 320 + co] = o;
}

// ---------------- MFMA GEMM: 128x128 tile, BK=64, XOR-swizzled LDS ----------------
// C[m,n] = act( sum_k A[m,k]*BT[n,k] + bias[n] ).
// LDS as 16B slots: slot(row,chunk) = row*8 + (chunk ^ (row&7))  -> fragment reads
// hit bank-group ((ss*4+quad)^(ml&7)): all 8 groups covered, 2 lanes each = free.
template <int LDA, int LDB, int LDC, int NK, int NBIAS, bool RELU>
__global__ __launch_bounds__(256) void gemm_kernel(const bf16_t* __restrict__ A,
                                                   const bf16_t* __restrict__ BT,
                                                   const float* __restrict__ bias,
                                                   bf16_t* __restrict__ C) {
  __shared__ __align__(16) bf16_t As[128 * 64];  // 16 KB
  __shared__ __align__(16) bf16_t Bs[128 * 64];  // 16 KB

  const int tid = threadIdx.x;
  const int lane = tid & 63;
  const int wave = tid >> 6;
  const int ml = lane & 15, quad = lane >> 4;
  const int wm = (wave & 1) * 64, wn = (wave >> 1) * 64;
  const int kx = ml & 7;  // fragment-read swizzle key
  const size_t bm = (size_t)blockIdx.x * 128;
  const size_t bnn = (size_t)blockIdx.y * 128;

  // staging: thread t, iter it -> slot s = it*256+t; row = it*32 + (t>>3),
  // lds chunk = t&7, global chunk = (t&7) ^ (row&7) = (t&7) ^ ((t>>3)&7)
  const int srow = tid >> 3;
  const int scg = (tid & 7) ^ (srow & 7);
  const bf16_t* ag = A + (bm + srow) * LDA + scg * 8;
  const bf16_t* bg = BT + (bnn + srow) * LDB + scg * 8;

  f32x4 acc[4][4];
  #pragma unroll
  for (int r = 0; r < 4; r++)
    #pragma unroll
    for (int c = 0; c < 4; c++) acc[r][c] = (f32x4){0.f, 0.f, 0.f, 0.f};

  for (int kb = 0; kb < NK; kb++) {
    const int kof = kb * 64;
    #pragma unroll
    for (int it = 0; it < 4; it++) {
      g2l16(ag + (size_t)it * 32 * LDA + kof, (void*)&As[((size_t)it * 256 + tid) * 8]);
      g2l16(bg + (size_t)it * 32 * LDB + kof, (void*)&Bs[((size_t)it * 256 + tid) * 8]);
    }
    __syncthreads();  // compiler drains vmcnt -> LDS ready

    #pragma unroll
    for (int ss = 0; ss < 2; ss++) {
      const int ck = (ss * 4 + quad) ^ kx;
      bf16x8 aF[4], bF[4];
      #pragma unroll
      for (int mf = 0; mf < 4; mf++)
        aF[mf] = *(const bf16x8*)&As[((wm + mf * 16 + ml) * 8 + ck) * 8];
      #pragma unroll
      for (int nf = 0; nf < 4; nf++)
        bF[nf] = *(const bf16x8*)&Bs[((wn + nf * 16 + ml) * 8 + ck) * 8];
      #pragma unroll
      for (int mf = 0; mf < 4; mf++)
        #pragma unroll
        for (int nf = 0; nf < 4; nf++)
          acc[mf][nf] = __builtin_amdgcn_mfma_f32_16x16x32_bf16(aF[mf], bF[nf], acc[mf][nf], 0, 0, 0);
    }
    __syncthreads();
  }

  // epilogue: C/D layout col=lane&15, row=quad*4+reg
  #pragma unroll
  for (int nf = 0; nf < 4; nf++) {
    const int colg = (int)bnn + wn + nf * 16 + ml;
    const float bv = (colg < NBIAS) ? bias[colg] : 0.f;
    #pragma unroll
    for (int mf = 0; mf < 4; mf++) {
      #pragma unroll
      for (int i = 0; i < 4; i++) {
        const size_t rowg = bm + wm + mf * 16 + quad * 4 + i;
        float v = acc[mf][nf][i] + bv;
        if (RELU) v = fmaxf(v, 0.f);
        C[rowg * LDC + colg] = (bf16_t)v;
      }
    }
  }
}

// ---------------- BN ----------------
__global__ void bn_stats_kernel(const bf16_t* __restrict__ H2, float* __restrict__ sums,
                                float* __restrict__ sumsq, int N) {
  const int col = threadIdx.x;
  if (col >= 300) return;
  const int r0 = blockIdx.x * 128;
  const int r1 = (r0 + 128 < N) ? r0 + 128 : N;
  float s = 0.f, ss = 0.f;
  #pragma unroll 4
  for (int r = r0; r < r1; r++) {
    float v = (float)H2[(size_t)r * 384 + col];
    s += v;
    ss += v * v;
  }
  atomicAdd(&sums[col], s);
  atomicAdd(&sumsq[col], ss);
}

__global__ void bn_params_kernel(const float* __restrict__ sums, const float* __restrict__ sumsq,
                                 const float* __restrict__ gamma, const float* __restrict__ beta,
                                 float* __restrict__ scale, float* __restrict__ shift, int N) {
  const int col = threadIdx.x;
  if (col >= 384) return;
  if (col >= 300) {  // pad cols: force h pad to 0
    scale[col] = 0.f;
    shift[col] = 0.f;
    return;
  }
  const float inv = 1.f / (float)N;
  const float mean = sums[col] * inv;
  float var = sumsq[col] * inv - mean * mean;
  if (var < 0.f) var = 0.f;
  const float sc = gamma[col] * rsqrtf(var + 1e-5f);
  scale[col] = sc;
  shift[col] = beta[col] - mean * sc;
}

// wave per node, lane<40 handles 8 cols
__global__ void bn_apply_kernel(const bf16_t* __restrict__ H2, const float* __restrict__ scale,
                                const float* __restrict__ shift, bf16_t* __restrict__ h,
                                float* __restrict__ out, int relu, int last, int N) {
  const int w = (blockIdx.x * blockDim.x + threadIdx.x) >> 6;
  const int lane = threadIdx.x & 63;
  if (w >= N || lane >= 40) return;
  const int co = lane * 8;
  bf16x8 v8 = *(const bf16x8*)&H2[(size_t)w * 384 + co];
  f32x4 s0 = *(const f32x4*)&scale[co];
  f32x4 s1 = *(const f32x4*)&scale[co + 4];
  f32x4 t0 = *(const f32x4*)&shift[co];
  f32x4 t1 = *(const f32x4*)&shift[co + 4];
  float vv[8];
  #pragma unroll
  for (int j = 0; j < 8; j++) {
    float sc = (j < 4) ? s0[j] : s1[j - 4];
    float sh = (j < 4) ? t0[j] : t1[j - 4];
    float v = (float)v8[j] * sc + sh;
    if (relu) v = fmaxf(v, 0.f);
    vv[j] = v;
  }
  if (!last) {
    bf16x8 o;
    #pragma unroll
    for (int j = 0; j < 8; j++) o[j] = (bf16_t)vv[j];
    *(bf16x8*)&h[(size_t)w * 320 + co] = o;
  } else {
    #pragma unroll
    for (int j = 0; j < 8; j++)
      if (co + j < 300) out[(size_t)w * 300 + co + j] = vv[j];
  }
}

// ---------------- launch ----------------
extern "C" void kernel_launch(void* const* d_in, const int* in_sizes, int n_in,
                              void* d_out, int out_size, void* d_ws, size_t ws_size,
                              hipStream_t stream) {
  const int* x = (const int*)d_in[0];
  const int* ei = (const int*)d_in[1];
  const int* ea = (const int*)d_in[2];
  const float* xe1 = (const float*)d_in[3];
  const float* xe2 = (const float*)d_in[4];
  const float* ee1 = (const float*)d_in[5];
  const float* ee2 = (const float*)d_in[6];
  const float* w1 = (const float*)d_in[7];
  const float* b1 = (const float*)d_in[8];
  const float* w2 = (const float*)d_in[9];
  const float* b2 = (const float*)d_in[10];
  const float* gam = (const float*)d_in[11];
  const float* bet = (const float*)d_in[12];

  const int N = in_sizes[0] / 2;   // 100000
  const int E = in_sizes[1] / 2;   // 200000
  const int Mt = (N + 127) / 128;  // 782
  const size_t Mp = (size_t)Mt * 128;

  char* p = (char*)d_ws;
  auto take = [&](size_t b) -> char* {
    char* r = p;
    p += (b + 255) & ~(size_t)255;
    return r;
  };
  bf16_t* h    = (bf16_t*)take(Mp * 320 * 2);
  bf16_t* agg  = (bf16_t*)take(Mp * 320 * 2);
  bf16_t* C1   = (bf16_t*)take(Mp * 640 * 2);
  bf16_t* H2   = (bf16_t*)take(Mp * 384 * 2);
  bf16_t* W1bT = (bf16_t*)take((size_t)5 * 640 * 320 * 2);
  bf16_t* W2bT = (bf16_t*)take((size_t)5 * 384 * 640 * 2);
  bf16_t* T12  = (bf16_t*)take((size_t)5 * 21 * 320 * 2);
  int* deg     = (int*)take((size_t)N * 4);
  int* rowptr  = (int*)take((size_t)(N + 1) * 4);
  int* cursor  = (int*)take((size_t)N * 4);
  int* part    = (int*)take(1024 * 4);
  int* epack   = (int*)take((size_t)E * 4);
  float* sums  = (float*)take(384 * 4);
  float* sumsq = (float*)take(384 * 4);
  float* scale = (float*)take(384 * 4);
  float* shift = (float*)take(384 * 4);

  // agg pad rows must be exact zeros for GEMM1 (aggregate writes rows<N only)
  hipMemsetAsync(agg, 0, Mp * 320 * 2, stream);
  hipMemsetAsync(deg, 0, (size_t)N * 4, stream);

  const int nwb = (N + 3) / 4;  // wave-per-node, 4 waves per 256-thread block
  embed_kernel<<<nwb, 256, 0, stream>>>(x, xe1, xe2, h, N);

  count_deg_kernel<<<(E + 255) / 256, 256, 0, stream>>>(ei, deg, E);
  const int nsb = (N + 255) / 256;  // 391 (<=1024 for scan_block)
  scan_partial_kernel<<<nsb, 256, 0, stream>>>(deg, part, N);
  scan_block_kernel<<<1, 1024, 0, stream>>>(part, nsb);
  scan_final_kernel<<<nsb, 256, 0, stream>>>(deg, part, rowptr, cursor, N, E);
  fill_csr_kernel<<<(E + 255) / 256, 256, 0, stream>>>(ei, ea, cursor, epack, E);

  convert_w1_kernel<<<(5 * 640 * 320 + 255) / 256, 256, 0, stream>>>(w1, W1bT);
  convert_w2_kernel<<<(5 * 384 * 640 + 255) / 256, 256, 0, stream>>>(w2, W2bT);
  build_t12_kernel<<<(5 * 21 * 320 + 255) / 256, 256, 0, stream>>>(ee1, ee2, T12);

  for (int l = 0; l < 5; l++) {
    aggregate_kernel<<<nwb, 256, 0, stream>>>(h, rowptr, epack, T12 + (size_t)l * 21 * 320,
                                              agg, N);
    // GEMM1: [Mp,320] x W1T[640,320] -> C1[Mp,640], bias b1 (600), ReLU
    gemm_kernel<320, 320, 640, 5, 600, true>
        <<<dim3(Mt, 5), 256, 0, stream>>>(agg, W1bT + (size_t)l * 640 * 320,
                                          b1 + (size_t)l * 600, C1);
    // GEMM2: [Mp,640] x W2T[384,640] -> H2[Mp,384], bias b2 (300)
    gemm_kernel<640, 640, 384, 10, 300, false>
        <<<dim3(Mt, 3), 256, 0, stream>>>(C1, W2bT + (size_t)l * 384 * 640,
                                          b2 + (size_t)l * 300, H2);
    hipMemsetAsync(sums, 0, 384 * 4, stream);
    hipMemsetAsync(sumsq, 0, 384 * 4, stream);
    bn_stats_kernel<<<Mt, 320, 0, stream>>>(H2, sums, sumsq, N);
    bn_params_kernel<<<1, 384, 0, stream>>>(sums, sumsq, gam + (size_t)l * 300,
                                            bet + (size_t)l * 300, scale, shift, N);
    bn_apply_kernel<<<nwb, 256, 0, stream>>>(H2, scale, shift, h, (float*)d_out,
                                             (l < 4) ? 1 : 0, (l == 4) ? 1 : 0, N);
  }
}